// Round 1
// baseline (334.769 us; speedup 1.0000x reference)
//
#include <hip/hip_runtime.h>
#include <hip/hip_fp16.h>

#define N_NODES 100000
#define N_EDGES 1600000
#define CH 128
#define OCH 64
#define NBUCKET 391   // ceil(100000/256) dst-buckets of 256 nodes
#define CAP 8192      // bucket capacity (mean 4092, sd ~64)
#define BIN_CHUNK 4096

typedef _Float16 half8 __attribute__((ext_vector_type(8)));
typedef float f32x4 __attribute__((ext_vector_type(4)));

__device__ __forceinline__ ushort f2h(float f) {
    _Float16 h = (_Float16)f;
    return *(ushort*)&h;
}

__device__ __forceinline__ uint pkadd(uint a, uint b) {
    __half2 r = __hadd2(*(__half2*)&a, *(__half2*)&b);
    return *(uint*)&r;
}

// XOR-swizzled f16 offset inside a [rows][128] f16 tile (r6-proven, 0 conflicts).
__device__ __forceinline__ int swz(int row, int k) {
    return row * 128 + ((((k >> 3) ^ (row & 15)) << 3) | (k & 7));
}

// ---------------- CSR build: LDS-staged counting sort (r6-proven shape) ----------------

__global__ __launch_bounds__(512) void k_bin(const int* __restrict__ src,
                                             const int* __restrict__ dst,
                                             int* __restrict__ bfill,
                                             int* __restrict__ bin) {
    __shared__ int hist[512];
    __shared__ int wbase[512];
    __shared__ int cur[512];
    const int t = threadIdx.x;
    const int e0 = blockIdx.x * BIN_CHUNK;

    hist[t] = 0;
    __syncthreads();

    int ss[8], bb[8], dl[8];
#pragma unroll
    for (int j = 0; j < 8; ++j) {
        int e = e0 + j * 512 + t;
        bb[j] = -1;
        if (e < N_EDGES) {
            int s = src[e], d = dst[e];
            ss[j] = s; dl[j] = d & 255; bb[j] = d >> 8;
            atomicAdd(&hist[bb[j]], 1);
        }
    }
    __syncthreads();

    int v = hist[t];
    for (int off = 1; off < 512; off <<= 1) {
        int tv = (t >= off) ? hist[t - off] : 0;
        __syncthreads();
        hist[t] += tv;
        __syncthreads();
    }
    int excl = hist[t] - v;
    if (t < NBUCKET && v > 0) {
        int gb = atomicAdd(&bfill[t], v);
        wbase[t] = gb - excl;
    }
    cur[t] = excl;
    __syncthreads();

#pragma unroll
    for (int j = 0; j < 8; ++j) {
        if (bb[j] >= 0) {
            int p = atomicAdd(&cur[bb[j]], 1);
            bin[bb[j] * CAP + wbase[bb[j]] + p] = (ss[j] << 8) | dl[j];
        }
    }
}

// block 0: exclusive scan of bucket fills. blocks 1..80: weight prep (fused launch).
__global__ __launch_bounds__(512) void k_scan_prep(const int* __restrict__ bfill,
                                                   int* __restrict__ bbase,
                                                   const float* __restrict__ W1,
                                                   const float* __restrict__ W2,
                                                   const float* __restrict__ Wo,
                                                   ushort* __restrict__ W1s,
                                                   ushort* __restrict__ W2s,
                                                   ushort* __restrict__ WoTs) {
    if (blockIdx.x == 0) {
        __shared__ int tmp[512];
        int t = threadIdx.x;
        int v = (t < NBUCKET) ? bfill[t] : 0;
        tmp[t] = v;
        __syncthreads();
        for (int off = 1; off < 512; off <<= 1) {
            int tv = (t >= off) ? tmp[t - off] : 0;
            __syncthreads();
            tmp[t] += tv;
            __syncthreads();
        }
        if (t < NBUCKET) bbase[t] = tmp[t] - v;
    } else {
        int i = (blockIdx.x - 1) * 512 + threadIdx.x;  // 0..40959
        if (i < 16384) {
            int k = i >> 7, n = i & 127;
            W1s[swz(n, k)] = f2h(W1[i]);
        } else if (i < 32768) {
            int j = i - 16384, k = j >> 7, n = j & 127;
            W2s[swz(n, k)] = f2h(W2[j]);
        } else if (i < 40960) {
            int j = i - 32768, k = j >> 6, n = j & 63;
            WoTs[swz(n, k)] = f2h(Wo[j]);
        }
    }
}

__global__ __launch_bounds__(256) void k_build(const int* __restrict__ bfill,
                                               const int* __restrict__ bbase,
                                               const int* __restrict__ bin,
                                               int* __restrict__ esrc,
                                               int* __restrict__ start,
                                               int* __restrict__ cnt,
                                               float* __restrict__ dis) {
    __shared__ int cnt_l[256];
    __shared__ int cur_l[256];
    __shared__ int sortbuf[CAP];
    const int t = threadIdx.x;
    const int b = blockIdx.x;
    const int n = bfill[b];
    const int base = bbase[b];
    const int* brec = bin + b * CAP;

    cnt_l[t] = 0;
    __syncthreads();
    for (int i = t; i < n; i += 256)
        atomicAdd(&cnt_l[brec[i] & 255], 1);
    __syncthreads();

    int v = cnt_l[t];
    for (int off = 1; off < 256; off <<= 1) {
        int tv = (t >= off) ? cnt_l[t - off] : 0;
        __syncthreads();
        cnt_l[t] += tv;
        __syncthreads();
    }
    int excl = cnt_l[t] - v;
    int node = b * 256 + t;
    if (node < N_NODES) {
        start[node] = base + excl;
        cnt[node] = v;
        dis[node] = rsqrtf((float)(v + 1));  // +1 self-loop
    }
    cur_l[t] = excl;
    __syncthreads();

    for (int i = t; i < n; i += 256) {
        int rec = brec[i];
        int p = atomicAdd(&cur_l[rec & 255], 1);
        sortbuf[p] = rec >> 8;
    }
    __syncthreads();
    for (int i = t; i < n; i += 256)
        esrc[base + i] = sortbuf[i];
}

// ---------------- MFMA GEMM: out_f16[r] = dis[r] * (A[r] @ W) (r6-proven) ----------------

template <typename IT>
__global__ __launch_bounds__(256) void k_gemm_mfma(const IT* __restrict__ A,
                                                   const ushort* __restrict__ Ws,
                                                   const float* __restrict__ dis,
                                                   ushort* __restrict__ out) {
    __shared__ ushort sB[128 * 128];
    __shared__ ushort sA[64 * 128];
    const int tid = threadIdx.x;
    const int row0 = blockIdx.x * 64;

    for (int i = tid; i < 2048; i += 256)
        ((float4*)sB)[i] = ((const float4*)Ws)[i];

    for (int i = tid; i < 2048; i += 256) {
        int m = i >> 5, u = i & 31, k4 = u << 2;
        int r = row0 + m;
        ushort4 pk = make_ushort4(0, 0, 0, 0);
        if (r < N_NODES) {
            if constexpr (sizeof(IT) == 4) {
                float4 a = ((const float4*)A)[r * 32 + u];
                pk = make_ushort4(f2h(a.x), f2h(a.y), f2h(a.z), f2h(a.w));
            } else {
                pk = ((const ushort4*)A)[r * 32 + u];
            }
        }
        *(ushort4*)&sA[swz(m, k4)] = pk;
    }
    __syncthreads();

    const int lane = tid & 63, wv = tid >> 6;
    const int mrow = lane & 15, quad = lane >> 4;
    f32x4 acc[8] = {};
#pragma unroll
    for (int kc = 0; kc < 4; ++kc) {
        int g = kc * 4 + quad;
        half8 a = *(const half8*)&sA[(wv * 16 + mrow) * 128 + ((g ^ mrow) << 3)];
#pragma unroll
        for (int nt = 0; nt < 8; ++nt) {
            half8 b = *(const half8*)&sB[(nt * 16 + mrow) * 128 + ((g ^ mrow) << 3)];
            acc[nt] = __builtin_amdgcn_mfma_f32_16x16x32_f16(a, b, acc[nt], 0, 0, 0);
        }
    }

    const int rbase = row0 + wv * 16 + quad * 4;
    float ds[4];
#pragma unroll
    for (int rg = 0; rg < 4; ++rg)
        ds[rg] = (rbase + rg < N_NODES) ? dis[rbase + rg] : 0.f;
#pragma unroll
    for (int nt = 0; nt < 8; ++nt) {
#pragma unroll
        for (int rg = 0; rg < 4; ++rg) {
            int r = rbase + rg;
            if (r < N_NODES) out[r * 128 + nt * 16 + mrow] = f2h(acc[nt][rg] * ds[rg]);
        }
    }
}

// ---------------- CSR aggregation: uint4 loads, quarter-wave per edge ----------------
// out[v] = relu(dis[v] * (sum_e h'[src_e] + h'[v]) + bias), fp16 pk accumulate.
// One wave per node; 16 lanes per edge row (16B/lane); 4 edges/load-instr,
// 4 loads in flight per quarter (16 edges/wave outstanding).

__global__ __launch_bounds__(256) void k_agg(const int* __restrict__ start,
                                             const int* __restrict__ cnt,
                                             const int* __restrict__ esrc,
                                             const ushort* __restrict__ h,
                                             const float* __restrict__ dis,
                                             const float* __restrict__ bias,
                                             ushort* __restrict__ out) {
    const int v = blockIdx.x * 4 + (threadIdx.x >> 6);
    const int lane = threadIdx.x & 63, q = lane >> 4, l = lane & 15;
    const uint4* h16 = (const uint4*)h;

    int n = cnt[v];
    const int* ep = esrc + start[v];

    uint4 aA = make_uint4(0, 0, 0, 0), aB = make_uint4(0, 0, 0, 0);
    int i = q;
    for (; i + 12 < n; i += 16) {  // this quarter: edges i, i+4, i+8, i+12
        int s0 = ep[i], s1 = ep[i + 4], s2 = ep[i + 8], s3 = ep[i + 12];
        uint4 t0 = h16[s0 * 16 + l];
        uint4 t1 = h16[s1 * 16 + l];
        uint4 t2 = h16[s2 * 16 + l];
        uint4 t3 = h16[s3 * 16 + l];
        aA.x = pkadd(aA.x, t0.x); aA.y = pkadd(aA.y, t0.y);
        aA.z = pkadd(aA.z, t0.z); aA.w = pkadd(aA.w, t0.w);
        aB.x = pkadd(aB.x, t1.x); aB.y = pkadd(aB.y, t1.y);
        aB.z = pkadd(aB.z, t1.z); aB.w = pkadd(aB.w, t1.w);
        aA.x = pkadd(aA.x, t2.x); aA.y = pkadd(aA.y, t2.y);
        aA.z = pkadd(aA.z, t2.z); aA.w = pkadd(aA.w, t2.w);
        aB.x = pkadd(aB.x, t3.x); aB.y = pkadd(aB.y, t3.y);
        aB.z = pkadd(aB.z, t3.z); aB.w = pkadd(aB.w, t3.w);
    }
    for (; i < n; i += 4) {
        int s0 = ep[i];
        uint4 t0 = h16[s0 * 16 + l];
        aA.x = pkadd(aA.x, t0.x); aA.y = pkadd(aA.y, t0.y);
        aA.z = pkadd(aA.z, t0.z); aA.w = pkadd(aA.w, t0.w);
    }
    aA.x = pkadd(aA.x, aB.x); aA.y = pkadd(aA.y, aB.y);
    aA.z = pkadd(aA.z, aB.z); aA.w = pkadd(aA.w, aB.w);
    // reduce across the 4 quarters
    aA.x = pkadd(aA.x, (uint)__shfl_xor((int)aA.x, 16));
    aA.y = pkadd(aA.y, (uint)__shfl_xor((int)aA.y, 16));
    aA.z = pkadd(aA.z, (uint)__shfl_xor((int)aA.z, 16));
    aA.w = pkadd(aA.w, (uint)__shfl_xor((int)aA.w, 16));
    aA.x = pkadd(aA.x, (uint)__shfl_xor((int)aA.x, 32));
    aA.y = pkadd(aA.y, (uint)__shfl_xor((int)aA.y, 32));
    aA.z = pkadd(aA.z, (uint)__shfl_xor((int)aA.z, 32));
    aA.w = pkadd(aA.w, (uint)__shfl_xor((int)aA.w, 32));

    if (q == 0) {
        uint4 hv = h16[v * 16 + l];  // self-loop term h'[v]
        aA.x = pkadd(aA.x, hv.x); aA.y = pkadd(aA.y, hv.y);
        aA.z = pkadd(aA.z, hv.z); aA.w = pkadd(aA.w, hv.w);
        float s = dis[v];
        float2 a0 = __half22float2(*(__half2*)&aA.x);
        float2 a1 = __half22float2(*(__half2*)&aA.y);
        float2 a2 = __half22float2(*(__half2*)&aA.z);
        float2 a3 = __half22float2(*(__half2*)&aA.w);
        float4 b0 = ((const float4*)bias)[2 * l];
        float4 b1 = ((const float4*)bias)[2 * l + 1];
        a0.x = fmaxf(a0.x * s + b0.x, 0.f); a0.y = fmaxf(a0.y * s + b0.y, 0.f);
        a1.x = fmaxf(a1.x * s + b0.z, 0.f); a1.y = fmaxf(a1.y * s + b0.w, 0.f);
        a2.x = fmaxf(a2.x * s + b1.x, 0.f); a2.y = fmaxf(a2.y * s + b1.y, 0.f);
        a3.x = fmaxf(a3.x * s + b1.z, 0.f); a3.y = fmaxf(a3.y * s + b1.w, 0.f);
        __half2 o0 = __float22half2_rn(a0);
        __half2 o1 = __float22half2_rn(a1);
        __half2 o2 = __float22half2_rn(a2);
        __half2 o3 = __float22half2_rn(a3);
        ((uint4*)out)[v * 16 + l] =
            make_uint4(*(uint*)&o0, *(uint*)&o1, *(uint*)&o2, *(uint*)&o3);
    }
}

// ---------------- final MFMA: out_f32[N][64] = (x1+x2)@Wo + bo (r6-proven) ----------------

__global__ __launch_bounds__(256) void k_final_mfma(const ushort* __restrict__ x1,
                                                    const ushort* __restrict__ x2,
                                                    const ushort* __restrict__ Ws,
                                                    const float* __restrict__ bo,
                                                    float* __restrict__ out) {
    __shared__ ushort sB[64 * 128];
    __shared__ ushort sA[64 * 128];
    const int tid = threadIdx.x;
    const int row0 = blockIdx.x * 64;

    for (int i = tid; i < 1024; i += 256)
        ((float4*)sB)[i] = ((const float4*)Ws)[i];

    for (int i = tid; i < 2048; i += 256) {
        int m = i >> 5, u = i & 31, k4 = u << 2;
        int r = row0 + m;
        uint2 pk = make_uint2(0, 0);
        if (r < N_NODES) {
            uint2 ua = ((const uint2*)x1)[r * 32 + u];
            uint2 ub = ((const uint2*)x2)[r * 32 + u];
            __half2 s0 = __hadd2(*(__half2*)&ua.x, *(__half2*)&ub.x);
            __half2 s1 = __hadd2(*(__half2*)&ua.y, *(__half2*)&ub.y);
            pk = make_uint2(*(uint*)&s0, *(uint*)&s1);
        }
        *(uint2*)&sA[swz(m, k4)] = pk;
    }
    __syncthreads();

    const int lane = tid & 63, wv = tid >> 6;
    const int mrow = lane & 15, quad = lane >> 4;
    f32x4 acc[4] = {};
#pragma unroll
    for (int kc = 0; kc < 4; ++kc) {
        int g = kc * 4 + quad;
        half8 a = *(const half8*)&sA[(wv * 16 + mrow) * 128 + ((g ^ mrow) << 3)];
#pragma unroll
        for (int nt = 0; nt < 4; ++nt) {
            half8 b = *(const half8*)&sB[(nt * 16 + mrow) * 128 + ((g ^ mrow) << 3)];
            acc[nt] = __builtin_amdgcn_mfma_f32_16x16x32_f16(a, b, acc[nt], 0, 0, 0);
        }
    }

    const int rbase = row0 + wv * 16 + quad * 4;
#pragma unroll
    for (int nt = 0; nt < 4; ++nt) {
        float bb = bo[nt * 16 + mrow];
#pragma unroll
        for (int rg = 0; rg < 4; ++rg) {
            int r = rbase + rg;
            if (r < N_NODES) out[(size_t)r * 64 + nt * 16 + mrow] = acc[nt][rg] + bb;
        }
    }
}

// ---------------- launch ----------------

extern "C" void kernel_launch(void* const* d_in, const int* in_sizes, int n_in,
                              void* d_out, int out_size, void* d_ws, size_t ws_size,
                              hipStream_t stream) {
    const float* x  = (const float*)d_in[0];
    const int*   ei = (const int*)d_in[1];
    const int*   src = ei;
    const int*   dst = ei + N_EDGES;
    const float* W1 = (const float*)d_in[2];
    const float* b1 = (const float*)d_in[3];
    const float* W2 = (const float*)d_in[4];
    const float* b2 = (const float*)d_in[5];
    const float* Wo = (const float*)d_in[6];
    const float* bo = (const float*)d_in[7];
    float* out = (float*)d_out;

    char* ws = (char*)d_ws;
    int*    bfill  = (int*)ws;            ws += 2048;
    int*    bbase  = (int*)ws;            ws += 2048;
    int*    cnt    = (int*)ws;            ws += 400000;
    int*    start  = (int*)ws;            ws += 400000;
    float*  dis    = (float*)ws;          ws += 400000;
    int*    bin    = (int*)ws;            ws += (size_t)NBUCKET * CAP * 4;  // 12.8 MB
    int*    esrc   = (int*)ws;            ws += (size_t)N_EDGES * 4;
    ushort* W1s    = (ushort*)ws;         ws += 32768;
    ushort* W2s    = (ushort*)ws;         ws += 32768;
    ushort* WoTs   = (ushort*)ws;         ws += 16384;
    ushort* h      = (ushort*)ws;         ws += (size_t)N_NODES * CH * 2;
    ushort* x1     = (ushort*)ws;         ws += (size_t)N_NODES * CH * 2;
    ushort* x2     = (ushort*)ws;

    const int B = 256;
    const int gG = (N_NODES + 63) / 64;   // 1563

    // CSR build (LDS-staged counting sort) + weight prep
    hipMemsetAsync(bfill, 0, 2048, stream);
    k_bin<<<(N_EDGES + BIN_CHUNK - 1) / BIN_CHUNK, 512, 0, stream>>>(src, dst, bfill, bin);
    k_scan_prep<<<81, 512, 0, stream>>>(bfill, bbase, W1, W2, Wo, W1s, W2s, WoTs);
    k_build<<<NBUCKET, 256, 0, stream>>>(bfill, bbase, bin, esrc, start, cnt, dis);

    // layer 1
    k_gemm_mfma<float><<<gG, B, 0, stream>>>(x, W1s, dis, h);
    k_agg<<<N_NODES / 4, B, 0, stream>>>(start, cnt, esrc, h, dis, b1, x1);

    // layer 2
    k_gemm_mfma<ushort><<<gG, B, 0, stream>>>(x1, W2s, dis, h);
    k_agg<<<N_NODES / 4, B, 0, stream>>>(start, cnt, esrc, h, dis, b2, x2);

    // output projection
    k_final_mfma<<<gG, B, 0, stream>>>(x1, x2, WoTs, bo, out);
}